// Round 7
// baseline (407.675 us; speedup 1.0000x reference)
//
#include <hip/hip_runtime.h>
#include <hip/hip_cooperative_groups.h>

namespace cg = cooperative_groups;

#define N_NODES 50000
#define N_PAD   50048
#define N_EDGES 800000
#define NBKT    196     // node buckets of 256 rows; ALSO the cooperative grid size
#define ESPAN   4096    // edges per front block (196*4096 >= 800000)
#define BCAP    4992    // LDS staging cap per bucket (mean 4096)

typedef __attribute__((ext_vector_type(8))) short bf16x8;
typedef __attribute__((ext_vector_type(4))) float f32x4;

__device__ __forceinline__ unsigned short f2bf(float f) {
    unsigned u = __float_as_uint(f);
    u = (u + 0x7fffu + ((u >> 16) & 1u)) >> 16;
    return (unsigned short)u;
}

__device__ __forceinline__ float fsig(float x) {          // fast sigmoid
    x = fminf(fmaxf(x, -30.f), 30.f);
    float t = __expf(x);
    return __fdividef(t, 1.f + t);
}
__device__ __forceinline__ float ftanh(float x) {         // fast tanh
    x = fminf(fmaxf(x, -15.f), 15.f);
    float t = __expf(2.f * x);
    return 1.f - __fdividef(2.f, t + 1.f);
}

// ---------------------------------------------------------------- k_front (cooperative):
// P0: edge bucket-hist || XH interleave || Wf fold || ball      (grid-stride)
// P1: per-bucket exclusive scan of hist over 196 blocks          (block b = bucket b)
// P2: scatter packed edges into bucket-grouped ebuf              (block b = edge span b)
// P3: per-bucket CSR build -> rp, dinv, cw=(col, w*dinv[r])      (block b = bucket b)
// No global atomics anywhere; LDS atomics only.

struct FrontArgs {
    const void* eiraw; const float* w;
    const float* X; const float* H; unsigned short* XH;
    unsigned* hist; unsigned* btot;
    unsigned long long* ebuf;
    int* rp; float* dinv; int2* cw;
    const float* Wxi; const float* Whi; const float* Wxf; const float* Whf;
    const float* Wxc; const float* Whc; const float* Wxo; const float* Who;
    const float* bxi; const float* bhi; const float* bxf; const float* bhf;
    const float* bxc; const float* bhc; const float* bxo; const float* bho;
    const float* bgi; const float* bgf; const float* bgc; const float* bgo;
    unsigned short* Wf; float* ball;
};

__global__ __launch_bounds__(1024) void k_front(FrontArgs a) {
    __shared__ unsigned long long se[BCAP];   // 39.9 KB build staging
    __shared__ unsigned s0[256];
    __shared__ unsigned cnt[256];
    __shared__ float    fsum[256];
    __shared__ unsigned cur[256];
    __shared__ unsigned boff[256];
    __shared__ float    dloc[256];
    __shared__ int      sflag;

    cg::grid_group grid = cg::this_grid();
    int b = blockIdx.x, t = threadIdx.x;
    int flat = b * 1024 + t;
    int e0 = b * ESPAN;
    int e1 = (e0 + ESPAN < N_EDGES) ? e0 + ESPAN : N_EDGES;

    // ---- P0a: int32/int64 detect on this span (int64 => odd 32-bit words all zero)
    if (t == 0) sflag = 0;
    if (t < NBKT) cnt[t] = 0u;
    __syncthreads();
    if (e0 + t < e1) {
        int sv = ((const int*)a.eiraw)[1 + 2 * (e0 + t)];
        if (sv) atomicOr(&sflag, 1);
    }
    __syncthreads();
    int is32 = sflag;

    // ---- P0b: bucket histogram of this span
    for (int e = e0 + t; e < e1; e += 1024) {
        int r = is32 ? ((const int*)a.eiraw)[e] : (int)(((const long long*)a.eiraw)[e]);
        atomicAdd(&cnt[r >> 8], 1u);
    }
    __syncthreads();
    if (t < NBKT) a.hist[(size_t)t * NBKT + b] = cnt[t];   // hist[bucket][block]

    // ---- P0c: XH interleave (grid-stride, 16 ch per unit)
    for (int u = flat; u < N_NODES * 8; u += NBKT * 1024) {
        int node = u >> 3, g = u & 7;
        const float* base = (g < 4) ? (a.X + (size_t)node * 64 + g * 16)
                                    : (a.H + (size_t)node * 64 + (g - 4) * 16);
        float4 v0 = ((const float4*)base)[0];
        float4 v1 = ((const float4*)base)[1];
        float4 v2 = ((const float4*)base)[2];
        float4 v3 = ((const float4*)base)[3];
        uint4 o0, o1;
        o0.x = (unsigned)f2bf(v0.x) | ((unsigned)f2bf(v0.y) << 16);
        o0.y = (unsigned)f2bf(v0.z) | ((unsigned)f2bf(v0.w) << 16);
        o0.z = (unsigned)f2bf(v1.x) | ((unsigned)f2bf(v1.y) << 16);
        o0.w = (unsigned)f2bf(v1.z) | ((unsigned)f2bf(v1.w) << 16);
        o1.x = (unsigned)f2bf(v2.x) | ((unsigned)f2bf(v2.y) << 16);
        o1.y = (unsigned)f2bf(v2.z) | ((unsigned)f2bf(v2.w) << 16);
        o1.z = (unsigned)f2bf(v3.x) | ((unsigned)f2bf(v3.y) << 16);
        o1.w = (unsigned)f2bf(v3.z) | ((unsigned)f2bf(v3.w) << 16);
        unsigned short* dst = a.XH + (size_t)node * 128 + g * 16;
        *(uint4*)dst = o0;
        *(uint4*)(dst + 8) = o1;
    }

    // ---- P0d: Wf fold [ks(12)][nt(16)][lane(64)][j(8)]; T0=V,T1=-U1,T2=2U2-V  + ball
    if (flat < 12288) {
        int l = flat & 63, nt = (flat >> 6) & 15, ks = flat >> 10;
        int n = nt * 16 + (l & 15);
        int g = n >> 6, c = n & 63;
        const float* WX = (g == 0) ? a.Wxi : (g == 1) ? a.Wxf : (g == 2) ? a.Wxc : a.Wxo;
        const float* WH = (g == 0) ? a.Whi : (g == 1) ? a.Whf : (g == 2) ? a.Whc : a.Who;
        int k0 = ks * 32 + (l >> 4) * 8;
        unsigned short ov[8];
#pragma unroll
        for (int j = 0; j < 8; j++) {
            int k = k0 + j;
            int bsel = k >> 7, ch = k & 127;
            const float* W = (ch < 64) ? WX : WH;
            int kk = ch & 63;
            float v;
            if (bsel == 0)      v = W[kk * 64 + c] - W[2 * 4096 + kk * 64 + c];
            else if (bsel == 1) v = -W[4096 + kk * 64 + c];
            else                v = 2.f * W[2 * 4096 + kk * 64 + c];
            ov[j] = f2bf(v);
        }
        uint4 o;
        o.x = (unsigned)ov[0] | ((unsigned)ov[1] << 16);
        o.y = (unsigned)ov[2] | ((unsigned)ov[3] << 16);
        o.z = (unsigned)ov[4] | ((unsigned)ov[5] << 16);
        o.w = (unsigned)ov[6] | ((unsigned)ov[7] << 16);
        *(uint4*)(a.Wf + (size_t)flat * 8) = o;
    } else if (flat < 12544) {
        int tt = flat - 12288;
        int g = tt >> 6, c = tt & 63;
        const float* BX = (g == 0) ? a.bxi : (g == 1) ? a.bxf : (g == 2) ? a.bxc : a.bxo;
        const float* BH = (g == 0) ? a.bhi : (g == 1) ? a.bhf : (g == 2) ? a.bhc : a.bho;
        const float* BG = (g == 0) ? a.bgi : (g == 1) ? a.bgf : (g == 2) ? a.bgc : a.bgo;
        a.ball[tt] = BX[c] + BH[c] + BG[c];
    }
    grid.sync();

    // ---- P1: bucket b's exclusive scan over its 196 block-counts (in place) + btot
    {
        unsigned* row = a.hist + (size_t)b * NBKT;
        unsigned v = (t < NBKT) ? row[t] : 0u;
        if (t < 256) s0[t] = v;
        __syncthreads();
        for (int d = 1; d < 256; d <<= 1) {
            unsigned x = 0u;
            if (t < 256 && t >= d) x = s0[t - d];
            __syncthreads();
            if (t < 256) s0[t] += x;
            __syncthreads();
        }
        if (t < NBKT) row[t] = s0[t] - v;
        if (t == 0) a.btot[b] = s0[255];
    }
    grid.sync();

    // ---- P2: scatter this span's edges into bucket-grouped ebuf
    {
        unsigned v = (t < NBKT) ? a.btot[t] : 0u;
        if (t < 256) s0[t] = v;
        __syncthreads();
        for (int d = 1; d < 256; d <<= 1) {
            unsigned x = 0u;
            if (t < 256 && t >= d) x = s0[t - d];
            __syncthreads();
            if (t < 256) s0[t] += x;
            __syncthreads();
        }
        if (t < NBKT) { boff[t] = (s0[t] - v) + a.hist[(size_t)t * NBKT + b]; cur[t] = 0u; }
        __syncthreads();
        for (int e = e0 + t; e < e1; e += 1024) {
            int r, c;
            if (is32) { r = ((const int*)a.eiraw)[e]; c = ((const int*)a.eiraw)[N_EDGES + e]; }
            else      { r = (int)(((const long long*)a.eiraw)[e]); c = (int)(((const long long*)a.eiraw)[N_EDGES + e]); }
            float wv = a.w[e];
            int bk = r >> 8;
            unsigned lr = atomicAdd(&cur[bk], 1u);       // LDS atomic only
            a.ebuf[boff[bk] + lr] = ((unsigned long long)(unsigned)r << 48)
                                  | (((unsigned long long)(unsigned)c & 0xffffull) << 32)
                                  | (unsigned long long)__float_as_uint(wv);
        }
    }
    grid.sync();

    // ---- P3: build bucket b -> rp (absolute), dinv, cw=(col, w*dinv[row])
    {
        unsigned v = (t < NBKT) ? a.btot[t] : 0u;
        if (t < 256) s0[t] = v;
        __syncthreads();
        for (int d = 1; d < 256; d <<= 1) {
            unsigned x = 0u;
            if (t < 256 && t >= d) x = s0[t - d];
            __syncthreads();
            if (t < 256) s0[t] += x;
            __syncthreads();
        }
        unsigned base = (b > 0) ? s0[b - 1] : 0u;       // inclusive scan -> bounds
        unsigned end  = s0[b];
        int n = (int)(end - base);
        if (b == 0 && t == 0) a.rp[N_NODES] = N_EDGES;
        if (t < 256) { cnt[t] = 0u; fsum[t] = 0.f; }
        __syncthreads();
        for (int i = t; i < n; i += 1024) {
            unsigned long long e = a.ebuf[base + i];
            if (i < BCAP) se[i] = e;
            unsigned lr = (unsigned)(e >> 48) & 255u;
            atomicAdd(&cnt[lr], 1u);
            atomicAdd(&fsum[lr], __uint_as_float((unsigned)(e & 0xffffffffu)));
        }
        __syncthreads();
        if (t < 256) s0[t] = cnt[t];
        __syncthreads();
        for (int d = 1; d < 256; d <<= 1) {
            unsigned x = 0u;
            if (t < 256 && t >= d) x = s0[t - d];
            __syncthreads();
            if (t < 256) s0[t] += x;
            __syncthreads();
        }
        if (t < 256) {
            unsigned excl = s0[t] - cnt[t];
            cur[t] = excl;
            float dg = fsum[t];
            float dv = (dg > 0.f) ? rsqrtf(dg) : 0.f;
            dloc[t] = dv;
            int row = b * 256 + t;
            if (row < N_NODES) { a.rp[row] = (int)(base + excl); a.dinv[row] = dv; }
        }
        __syncthreads();
        for (int i = t; i < n; i += 1024) {
            unsigned long long e = (i < BCAP) ? se[i] : a.ebuf[base + i];
            unsigned lr = (unsigned)(e >> 48) & 255u;
            unsigned p = atomicAdd(&cur[lr], 1u);        // LDS atomic only
            int c = (int)((e >> 32) & 0xffffu);
            float wd = __uint_as_float((unsigned)(e & 0xffffffffu)) * dloc[lr];
            a.cw[base + p] = make_int2(c, __float_as_int(wd));
        }
    }
}

// ---------------------------------------------------------------- SpMV: dst = A*src (bf16, fp32 accum)
// one wave per node; lane = channel pair; 8-deep masked gather groups.
// weight = cw.y (w*dinv[r]) * dinv[c]; dinv gather is independent + L2-resident (200 KB).

__global__ __launch_bounds__(256) void k_spmv_bf(const unsigned short* __restrict__ src,
                                                 unsigned short* __restrict__ dst,
                                                 const int* __restrict__ rp,
                                                 const int2* __restrict__ cw,
                                                 const float* __restrict__ dinv) {
    int wid = threadIdx.x >> 6, lane = threadIdx.x & 63;
    int node = blockIdx.x * 4 + wid;
    if (node >= N_NODES) return;
    int s = rp[node], e = rp[node + 1];
    float a0 = 0.f, a1 = 0.f;
    for (int jb = s; jb < e; jb += 8) {
        int2 cv[8]; float dv[8]; unsigned vv[8];
#pragma unroll
        for (int k = 0; k < 8; k++) {
            int j = jb + k;
            int jc = (j < e) ? j : (e - 1);       // clamp: stay in-bounds
            cv[k] = cw[jc];
            if (j >= e) cv[k].y = 0;              // zero weight for clamped slots
        }
#pragma unroll
        for (int k = 0; k < 8; k++)
            dv[k] = dinv[cv[k].x];
#pragma unroll
        for (int k = 0; k < 8; k++)
            vv[k] = *(const unsigned*)(src + (size_t)cv[k].x * 128 + lane * 2);
#pragma unroll
        for (int k = 0; k < 8; k++) {
            float wv = __int_as_float(cv[k].y) * dv[k];
            a0 = fmaf(wv, __uint_as_float(vv[k] << 16), a0);
            a1 = fmaf(wv, __uint_as_float(vv[k] & 0xffff0000u), a1);
        }
    }
    unsigned o = (unsigned)f2bf(a0) | ((unsigned)f2bf(a1) << 16);
    *(unsigned*)(dst + (size_t)node * 128 + lane * 2) = o;
}

// ---------------------------------------------------------------- MFMA GEMM [50000,384]@[384,256] + LSTM gates

__global__ __launch_bounds__(256) void k_gemm_mfma(
    const unsigned short* __restrict__ XH, const unsigned short* __restrict__ U1,
    const unsigned short* __restrict__ U2, const unsigned short* __restrict__ Wf,
    const float* __restrict__ ball, const float* __restrict__ C, float* __restrict__ out) {
    __shared__ __align__(16) uint4 Bs[2][1024];   // 2 x 16 KB

    int t = threadIdx.x;
    int wid = t >> 6, lane = t & 63;
    int col = lane & 15, quad = lane >> 4;
    int m0 = blockIdx.x * 64 + wid * 16;
    int arow = m0 + col;

    f32x4 acc[16];
#pragma unroll
    for (int i = 0; i < 16; i++) acc[i] = (f32x4){0.f, 0.f, 0.f, 0.f};

    const unsigned short* srcs[3] = {XH, U1, U2};

    bf16x8 a_cur = *(const bf16x8*)(srcs[0] + (size_t)arow * 128 + quad * 8);
    const uint4* g0 = (const uint4*)Wf;
    uint4 p0 = g0[t], p1 = g0[t + 256], p2 = g0[t + 512], p3 = g0[t + 768];

    for (int ks = 0; ks < 12; ks++) {
        uint4* dstb = Bs[ks & 1];
        dstb[t] = p0; dstb[t + 256] = p1; dstb[t + 512] = p2; dstb[t + 768] = p3;
        __syncthreads();
        bf16x8 a_nxt = a_cur;
        if (ks < 11) {
            int ks1 = ks + 1;
            const uint4* g = (const uint4*)(Wf + (size_t)ks1 * 8192);
            p0 = g[t]; p1 = g[t + 256]; p2 = g[t + 512]; p3 = g[t + 768];
            a_nxt = *(const bf16x8*)(srcs[ks1 >> 2] + (size_t)arow * 128 + (ks1 & 3) * 32 + quad * 8);
        }
        const unsigned short* B = (const unsigned short*)Bs[ks & 1];
#pragma unroll
        for (int nt = 0; nt < 16; nt++) {
            bf16x8 bfrag = *(const bf16x8*)(B + nt * 512 + lane * 8);
            acc[nt] = __builtin_amdgcn_mfma_f32_16x16x32_bf16(a_cur, bfrag, acc[nt], 0, 0, 0);
        }
        a_cur = a_nxt;
    }

    float bI[4], bF[4], bT[4], bO[4];
#pragma unroll
    for (int cq = 0; cq < 4; cq++) {
        int c = cq * 16 + col;
        bI[cq] = ball[c]; bF[cq] = ball[64 + c]; bT[cq] = ball[128 + c]; bO[cq] = ball[192 + c];
    }
#pragma unroll
    for (int r = 0; r < 4; r++) {
        int node = m0 + quad * 4 + r;
        if (node >= N_NODES) continue;
#pragma unroll
        for (int cq = 0; cq < 4; cq++) {
            int c = cq * 16 + col;
            float ig = fsig(acc[0 + cq][r]  + bI[cq]);
            float fg = fsig(acc[4 + cq][r]  + bF[cq]);
            float tg = ftanh(acc[8 + cq][r] + bT[cq]);
            float og = fsig(acc[12 + cq][r] + bO[cq]);
            float cv = fmaf(fg, C[(size_t)node * 64 + c], ig * tg);
            out[(size_t)node * 64 + c] = og * ftanh(cv);
            out[(size_t)N_NODES * 64 + (size_t)node * 64 + c] = cv;
        }
    }
}

// ---------------------------------------------------------------- launch

extern "C" void kernel_launch(void* const* d_in, const int* in_sizes, int n_in,
                              void* d_out, int out_size, void* d_ws, size_t ws_size,
                              hipStream_t stream) {
    const float* X   = (const float*)d_in[0];
    const void*  ei  = d_in[1];
    const float* w   = (const float*)d_in[2];
    const float* H   = (const float*)d_in[3];
    const float* C   = (const float*)d_in[4];
    const float* Wxi = (const float*)d_in[5];  const float* bxi = (const float*)d_in[6];
    const float* Whi = (const float*)d_in[7];  const float* bhi = (const float*)d_in[8];
    const float* Wxf = (const float*)d_in[9];  const float* bxf = (const float*)d_in[10];
    const float* Whf = (const float*)d_in[11]; const float* bhf = (const float*)d_in[12];
    const float* Wxc = (const float*)d_in[13]; const float* bxc = (const float*)d_in[14];
    const float* Whc = (const float*)d_in[15]; const float* bhc = (const float*)d_in[16];
    const float* Wxo = (const float*)d_in[17]; const float* bxo = (const float*)d_in[18];
    const float* Who = (const float*)d_in[19]; const float* bho = (const float*)d_in[20];
    const float* bgi = (const float*)d_in[21]; const float* bgf = (const float*)d_in[22];
    const float* bgc = (const float*)d_in[23]; const float* bgo = (const float*)d_in[24];
    float* out = (float*)d_out;

    char* ws = (char*)d_ws;
    size_t off = 0;
    auto alloc = [&](size_t bytes) -> char* {
        char* p = ws + off;
        off = (off + bytes + 255) & ~(size_t)255;
        return p;
    };
    unsigned* hist  = (unsigned*)alloc((size_t)NBKT * NBKT * 4);
    unsigned* btot  = (unsigned*)alloc((NBKT + 1) * 4);
    unsigned long long* ebuf = (unsigned long long*)alloc((size_t)N_EDGES * 8);
    int*   rp   = (int*)alloc((N_NODES + 1) * 4);
    float* dinv = (float*)alloc(N_NODES * 4);
    int2*  cw   = (int2*)alloc((size_t)(N_EDGES + 16) * 8);
    unsigned short* XH = (unsigned short*)alloc((size_t)N_PAD * 128 * 2);
    unsigned short* U1 = (unsigned short*)alloc((size_t)N_PAD * 128 * 2);
    unsigned short* U2 = (unsigned short*)alloc((size_t)N_PAD * 128 * 2);
    unsigned short* Wf = (unsigned short*)alloc((size_t)12 * 16 * 64 * 8 * 2);
    float* ball = (float*)alloc(256 * 4);
    (void)ws_size; (void)in_sizes; (void)n_in; (void)out_size;

    FrontArgs fa;
    fa.eiraw = ei; fa.w = w; fa.X = X; fa.H = H; fa.XH = XH;
    fa.hist = hist; fa.btot = btot; fa.ebuf = ebuf;
    fa.rp = rp; fa.dinv = dinv; fa.cw = cw;
    fa.Wxi = Wxi; fa.Whi = Whi; fa.Wxf = Wxf; fa.Whf = Whf;
    fa.Wxc = Wxc; fa.Whc = Whc; fa.Wxo = Wxo; fa.Who = Who;
    fa.bxi = bxi; fa.bhi = bhi; fa.bxf = bxf; fa.bhf = bhf;
    fa.bxc = bxc; fa.bhc = bhc; fa.bxo = bxo; fa.bho = bho;
    fa.bgi = bgi; fa.bgf = bgf; fa.bgc = bgc; fa.bgo = bgo;
    fa.Wf = Wf; fa.ball = ball;
    void* kargs[] = { &fa };
    hipLaunchCooperativeKernel((void*)k_front, dim3(NBKT), dim3(1024), kargs, 0u, stream);

    k_spmv_bf<<<(N_NODES + 3) / 4, 256, 0, stream>>>(XH, U1, rp, cw, dinv);
    k_spmv_bf<<<(N_NODES + 3) / 4, 256, 0, stream>>>(U1, U2, rp, cw, dinv);
    k_gemm_mfma<<<(N_NODES + 63) / 64, 256, 0, stream>>>(XH, U1, U2, Wf, ball, C, out);
}

// Round 8
// 267.466 us; speedup vs baseline: 1.5242x; 1.5242x over previous
//
#include <hip/hip_runtime.h>

#define N_NODES 50000
#define N_PAD   50048
#define N_EDGES 800000
#define NBE4    782     // edge blocks, 1024 edges each (4 per thread)
#define NB_IL2  1563    // interleave blocks, 16 ch per thread (50000*8/256)
#define NBKT    196     // node buckets of 256 rows (50000/256 rounded up)
#define BCAP    4992    // LDS staging cap per bucket (mean 4096, +14 sigma)

typedef __attribute__((ext_vector_type(8))) short bf16x8;
typedef __attribute__((ext_vector_type(4))) float f32x4;

__device__ __forceinline__ unsigned short f2bf(float f) {
    unsigned u = __float_as_uint(f);
    u = (u + 0x7fffu + ((u >> 16) & 1u)) >> 16;
    return (unsigned short)u;
}

__device__ __forceinline__ float fsig(float x) {          // fast sigmoid
    x = fminf(fmaxf(x, -30.f), 30.f);
    float t = __expf(x);
    return __fdividef(t, 1.f + t);
}
__device__ __forceinline__ float ftanh(float x) {         // fast tanh
    x = fminf(fmaxf(x, -15.f), 15.f);
    float t = __expf(2.f * x);
    return 1.f - __fdividef(2.f, t + 1.f);
}

// ---------------------------------------------------------------- k_prep: bucket-hist || interleave || wprep
// NO global atomics: edge phase only builds a per-block histogram over 196 row-buckets.

__global__ __launch_bounds__(256) void k_prep(
    const void* __restrict__ eiraw,
    unsigned* __restrict__ hist,
    const float* __restrict__ X, const float* __restrict__ H, unsigned short* __restrict__ XH,
    const float* __restrict__ Wxi, const float* __restrict__ Whi,
    const float* __restrict__ Wxf, const float* __restrict__ Whf,
    const float* __restrict__ Wxc, const float* __restrict__ Whc,
    const float* __restrict__ Wxo, const float* __restrict__ Who,
    const float* __restrict__ bxi, const float* __restrict__ bhi,
    const float* __restrict__ bxf, const float* __restrict__ bhf,
    const float* __restrict__ bxc, const float* __restrict__ bhc,
    const float* __restrict__ bxo, const float* __restrict__ bho,
    const float* __restrict__ bgi, const float* __restrict__ bgf,
    const float* __restrict__ bgc, const float* __restrict__ bgo,
    unsigned short* __restrict__ Wf, float* __restrict__ ball) {
    __shared__ int sflag;
    __shared__ unsigned cnt[NBKT];
    int b = blockIdx.x, t = threadIdx.x;
    if (b < NBE4) {
        if (t == 0) sflag = 0;
        if (t < NBKT) cnt[t] = 0;
        __syncthreads();
        int si = b * 1024 + t;                      // sample odd 32-bit words: all-zero => int64
        int sv = ((const int*)eiraw)[1 + 2 * si];
        if (sv) atomicOr(&sflag, 1);
        __syncthreads();
        int is32 = sflag;
#pragma unroll
        for (int k = 0; k < 4; k++) {
            int e = b * 1024 + k * 256 + t;
            if (e < N_EDGES) {
                int r = is32 ? ((const int*)eiraw)[e] : (int)(((const long long*)eiraw)[e]);
                atomicAdd(&cnt[r >> 8], 1u);
            }
        }
        __syncthreads();
        if (t < NBKT) hist[(size_t)t * NBE4 + b] = cnt[t];   // [bucket][block]
        return;
    }
    int bb = b - NBE4;
    if (bb < NB_IL2) {
        int tt = bb * 256 + t;                   // one thread per 16 channels
        int node = tt >> 3, g = tt & 7;
        if (node >= N_NODES) return;
        const float* base = (g < 4) ? (X + (size_t)node * 64 + g * 16)
                                    : (H + (size_t)node * 64 + (g - 4) * 16);
        float4 v0 = ((const float4*)base)[0];
        float4 v1 = ((const float4*)base)[1];
        float4 v2 = ((const float4*)base)[2];
        float4 v3 = ((const float4*)base)[3];
        uint4 o0, o1;
        o0.x = (unsigned)f2bf(v0.x) | ((unsigned)f2bf(v0.y) << 16);
        o0.y = (unsigned)f2bf(v0.z) | ((unsigned)f2bf(v0.w) << 16);
        o0.z = (unsigned)f2bf(v1.x) | ((unsigned)f2bf(v1.y) << 16);
        o0.w = (unsigned)f2bf(v1.z) | ((unsigned)f2bf(v1.w) << 16);
        o1.x = (unsigned)f2bf(v2.x) | ((unsigned)f2bf(v2.y) << 16);
        o1.y = (unsigned)f2bf(v2.z) | ((unsigned)f2bf(v2.w) << 16);
        o1.z = (unsigned)f2bf(v3.x) | ((unsigned)f2bf(v3.y) << 16);
        o1.w = (unsigned)f2bf(v3.z) | ((unsigned)f2bf(v3.w) << 16);
        unsigned short* dst = XH + (size_t)node * 128 + g * 16;
        *(uint4*)dst = o0;
        *(uint4*)(dst + 8) = o1;
        return;
    }
    bb -= NB_IL2;
    if (bb < 48) {
        // Wf layout: [ks(12)][nt(16)][lane(64)][j(8)] bf16; T0=V,T1=-U1,T2=2U2-V fold
        int flat = bb * 256 + t;
        int l = flat & 63, nt = (flat >> 6) & 15, ks = flat >> 10;
        int n = nt * 16 + (l & 15);
        int g = n >> 6, c = n & 63;
        const float* WX = (g == 0) ? Wxi : (g == 1) ? Wxf : (g == 2) ? Wxc : Wxo;
        const float* WH = (g == 0) ? Whi : (g == 1) ? Whf : (g == 2) ? Whc : Who;
        int k0 = ks * 32 + (l >> 4) * 8;
        unsigned short ov[8];
#pragma unroll
        for (int j = 0; j < 8; j++) {
            int k = k0 + j;
            int bsel = k >> 7, ch = k & 127;
            const float* W = (ch < 64) ? WX : WH;
            int kk = ch & 63;
            float v;
            if (bsel == 0)      v = W[kk * 64 + c] - W[2 * 4096 + kk * 64 + c];
            else if (bsel == 1) v = -W[4096 + kk * 64 + c];
            else                v = 2.f * W[2 * 4096 + kk * 64 + c];
            ov[j] = f2bf(v);
        }
        uint4 o;
        o.x = (unsigned)ov[0] | ((unsigned)ov[1] << 16);
        o.y = (unsigned)ov[2] | ((unsigned)ov[3] << 16);
        o.z = (unsigned)ov[4] | ((unsigned)ov[5] << 16);
        o.w = (unsigned)ov[6] | ((unsigned)ov[7] << 16);
        *(uint4*)(Wf + (size_t)flat * 8) = o;
    } else {
        int g = t >> 6, c = t & 63;
        const float* BX = (g == 0) ? bxi : (g == 1) ? bxf : (g == 2) ? bxc : bxo;
        const float* BH = (g == 0) ? bhi : (g == 1) ? bhf : (g == 2) ? bhc : bho;
        const float* BG = (g == 0) ? bgi : (g == 1) ? bgf : (g == 2) ? bgc : bgo;
        ball[t] = BX[c] + BH[c] + BG[c];
    }
}

// ---------------------------------------------------------------- k_bscan: per-bucket exclusive scan over 782 blocks (in place)

__global__ __launch_bounds__(256) void k_bscan(unsigned* __restrict__ hist, unsigned* __restrict__ btot) {
    __shared__ unsigned s[256];
    int j = blockIdx.x, t = threadIdx.x;
    unsigned* row = hist + (size_t)j * NBE4;
    unsigned v[4];
#pragma unroll
    for (int k = 0; k < 4; k++) {
        int i = t * 4 + k;
        v[k] = (i < NBE4) ? row[i] : 0u;
    }
    unsigned tsum = v[0] + v[1] + v[2] + v[3];
    s[t] = tsum; __syncthreads();
    for (int d = 1; d < 256; d <<= 1) {
        unsigned a = (t >= d) ? s[t - d] : 0u;
        __syncthreads();
        s[t] += a;
        __syncthreads();
    }
    unsigned run = s[t] - tsum;                  // exclusive over earlier threads
#pragma unroll
    for (int k = 0; k < 4; k++) {
        int i = t * 4 + k;
        if (i < NBE4) { unsigned c = v[k]; row[i] = run; run += c; }
    }
    if (t == 255) btot[j] = s[255];
}

// ---------------------------------------------------------------- k_btot: scan bucket totals -> bases; rp[N]=E

__global__ __launch_bounds__(256) void k_btot(const unsigned* __restrict__ btot,
                                              unsigned* __restrict__ bbase, int* __restrict__ rp) {
    __shared__ unsigned s[256];
    int t = threadIdx.x;
    unsigned v = (t < NBKT) ? btot[t] : 0u;
    s[t] = v; __syncthreads();
    for (int d = 1; d < 256; d <<= 1) {
        unsigned a = (t >= d) ? s[t - d] : 0u;
        __syncthreads();
        s[t] += a;
        __syncthreads();
    }
    if (t < NBKT) bbase[t] = s[t] - v;
    if (t == 0) { bbase[NBKT] = N_EDGES; rp[N_NODES] = N_EDGES; }
}

// ---------------------------------------------------------------- k_scat: scatter packed edges into bucket-grouped ebuf (no global atomics)

__global__ __launch_bounds__(256) void k_scat(const void* __restrict__ eiraw, const float* __restrict__ w,
                                              const unsigned* __restrict__ hist, const unsigned* __restrict__ bbase,
                                              unsigned long long* __restrict__ ebuf) {
    __shared__ int sflag;
    __shared__ unsigned boff[NBKT];
    __shared__ unsigned cur[NBKT];
    int b = blockIdx.x, t = threadIdx.x;
    if (t == 0) sflag = 0;
    if (t < NBKT) { boff[t] = bbase[t] + hist[(size_t)t * NBE4 + b]; cur[t] = 0u; }
    __syncthreads();
    int si = b * 1024 + t;
    int sv = ((const int*)eiraw)[1 + 2 * si];
    if (sv) atomicOr(&sflag, 1);
    __syncthreads();
    int is32 = sflag;
#pragma unroll
    for (int k = 0; k < 4; k++) {
        int e = b * 1024 + k * 256 + t;
        if (e < N_EDGES) {
            int r, c;
            if (is32) { r = ((const int*)eiraw)[e]; c = ((const int*)eiraw)[N_EDGES + e]; }
            else      { r = (int)(((const long long*)eiraw)[e]); c = (int)(((const long long*)eiraw)[N_EDGES + e]); }
            float wv = w[e];
            int bk = r >> 8;
            unsigned lr = atomicAdd(&cur[bk], 1u);       // LDS atomic only
            unsigned pos = boff[bk] + lr;
            ebuf[pos] = ((unsigned long long)(unsigned)r << 48)
                      | (((unsigned long long)(unsigned)c & 0xffffull) << 32)
                      | (unsigned long long)__float_as_uint(wv);
        }
    }
}

// ---------------------------------------------------------------- k_build: per-bucket CSR (rp absolute, dinv, packed rc, wraw)

__global__ __launch_bounds__(1024) void k_build(const unsigned long long* __restrict__ ebuf,
                                                const unsigned* __restrict__ bbase,
                                                int* __restrict__ rp, float* __restrict__ dinv,
                                                int* __restrict__ colp, float* __restrict__ wraw) {
    __shared__ unsigned long long se[BCAP];
    __shared__ unsigned cnt[256];
    __shared__ float wsum[256];
    __shared__ unsigned off[256];
    __shared__ unsigned cur[256];
    int b = blockIdx.x, t = threadIdx.x;
    unsigned base = bbase[b], end = bbase[b + 1];
    int n = (int)(end - base);
    if (t < 256) { cnt[t] = 0u; wsum[t] = 0.f; }
    __syncthreads();
    for (int i = t; i < n; i += 1024) {
        unsigned long long e = ebuf[base + i];
        if (i < BCAP) se[i] = e;
        unsigned lr = (unsigned)(e >> 48) & 255u;
        atomicAdd(&cnt[lr], 1u);
        atomicAdd(&wsum[lr], __uint_as_float((unsigned)(e & 0xffffffffu)));
    }
    __syncthreads();
    if (t < 256) off[t] = cnt[t];
    __syncthreads();
    for (int d = 1; d < 256; d <<= 1) {
        unsigned a = 0u;
        if (t < 256 && t >= d) a = off[t - d];
        __syncthreads();
        if (t < 256) off[t] += a;
        __syncthreads();
    }
    if (t < 256) {
        unsigned excl = off[t] - cnt[t];
        off[t] = excl;
        cur[t] = excl;
        int row = b * 256 + t;
        if (row < N_NODES) {
            rp[row] = (int)(base + excl);
            float dg = wsum[t];
            dinv[row] = (dg > 0.f) ? rsqrtf(dg) : 0.f;
        }
    }
    __syncthreads();
    for (int i = t; i < n; i += 1024) {
        unsigned long long e = (i < BCAP) ? se[i] : ebuf[base + i];
        unsigned lr = (unsigned)(e >> 48) & 255u;
        unsigned p = atomicAdd(&cur[lr], 1u);            // LDS atomic only
        int row = b * 256 + (int)lr;
        int c = (int)((e >> 32) & 0xffffu);
        colp[base + p] = (row << 16) | c;                // packed (r,c), both < 2^16
        wraw[base + p] = __uint_as_float((unsigned)(e & 0xffffffffu));
    }
}

// ---------------------------------------------------------------- k_nw: elementwise nw = dinv[r]*w*dinv[c] (dinv table is L2-hot, 200 KB)

__global__ __launch_bounds__(256) void k_nw(const int* __restrict__ colp, const float* __restrict__ wraw,
                                            const float* __restrict__ dinv, float* __restrict__ nwp) {
    int e = blockIdx.x * 256 + threadIdx.x;
    if (e >= N_EDGES) return;
    unsigned rc = (unsigned)colp[e];
    nwp[e] = dinv[rc >> 16] * wraw[e] * dinv[rc & 0xffffu];
}

// ---------------------------------------------------------------- SpMV: dst = A*src (bf16, fp32 accum) — lean form
// one wave per node; lane = channel pair; masked 8-edge groups keep 8 gathers in flight (no serial tail).

__global__ __launch_bounds__(256) void k_spmv_bf(const unsigned short* __restrict__ src,
                                                 unsigned short* __restrict__ dst,
                                                 const int* __restrict__ rp,
                                                 const int* __restrict__ colp, const float* __restrict__ nwp) {
    int wid = threadIdx.x >> 6, lane = threadIdx.x & 63;
    int node = blockIdx.x * 4 + wid;
    if (node >= N_NODES) return;
    int s = rp[node], e = rp[node + 1];
    float a0 = 0.f, a1 = 0.f;
    for (int jb = s; jb < e; jb += 8) {
        int   c[8]; float wv[8]; unsigned vv[8];
#pragma unroll
        for (int k = 0; k < 8; k++) {
            int j = jb + k;
            int jc = (j < e) ? j : (e - 1);       // clamp: stay in-bounds, weight zeroed
            c[k]  = colp[jc] & 0xffff;
            wv[k] = (j < e) ? nwp[jc] : 0.f;
        }
#pragma unroll
        for (int k = 0; k < 8; k++)
            vv[k] = *(const unsigned*)(src + (size_t)c[k] * 128 + lane * 2);
#pragma unroll
        for (int k = 0; k < 8; k++) {
            a0 = fmaf(wv[k], __uint_as_float(vv[k] << 16), a0);
            a1 = fmaf(wv[k], __uint_as_float(vv[k] & 0xffff0000u), a1);
        }
    }
    unsigned o = (unsigned)f2bf(a0) | ((unsigned)f2bf(a1) << 16);
    *(unsigned*)(dst + (size_t)node * 128 + lane * 2) = o;
}

// ---------------------------------------------------------------- MFMA GEMM [50000,384]@[384,256] + LSTM gates

__global__ __launch_bounds__(256) void k_gemm_mfma(
    const unsigned short* __restrict__ XH, const unsigned short* __restrict__ U1,
    const unsigned short* __restrict__ U2, const unsigned short* __restrict__ Wf,
    const float* __restrict__ ball, const float* __restrict__ C, float* __restrict__ out) {
    __shared__ __align__(16) uint4 Bs[2][1024];   // 2 x 16 KB

    int t = threadIdx.x;
    int wid = t >> 6, lane = t & 63;
    int col = lane & 15, quad = lane >> 4;
    int m0 = blockIdx.x * 64 + wid * 16;
    int arow = m0 + col;

    f32x4 acc[16];
#pragma unroll
    for (int i = 0; i < 16; i++) acc[i] = (f32x4){0.f, 0.f, 0.f, 0.f};

    const unsigned short* srcs[3] = {XH, U1, U2};

    bf16x8 a_cur = *(const bf16x8*)(srcs[0] + (size_t)arow * 128 + quad * 8);
    const uint4* g0 = (const uint4*)Wf;
    uint4 p0 = g0[t], p1 = g0[t + 256], p2 = g0[t + 512], p3 = g0[t + 768];

    for (int ks = 0; ks < 12; ks++) {
        uint4* dstb = Bs[ks & 1];
        dstb[t] = p0; dstb[t + 256] = p1; dstb[t + 512] = p2; dstb[t + 768] = p3;
        __syncthreads();
        bf16x8 a_nxt = a_cur;
        if (ks < 11) {
            int ks1 = ks + 1;
            const uint4* g = (const uint4*)(Wf + (size_t)ks1 * 8192);
            p0 = g[t]; p1 = g[t + 256]; p2 = g[t + 512]; p3 = g[t + 768];
            a_nxt = *(const bf16x8*)(srcs[ks1 >> 2] + (size_t)arow * 128 + (ks1 & 3) * 32 + quad * 8);
        }
        const unsigned short* B = (const unsigned short*)Bs[ks & 1];
#pragma unroll
        for (int nt = 0; nt < 16; nt++) {
            bf16x8 bfrag = *(const bf16x8*)(B + nt * 512 + lane * 8);
            acc[nt] = __builtin_amdgcn_mfma_f32_16x16x32_bf16(a_cur, bfrag, acc[nt], 0, 0, 0);
        }
        a_cur = a_nxt;
    }

    float bI[4], bF[4], bT[4], bO[4];
#pragma unroll
    for (int cq = 0; cq < 4; cq++) {
        int c = cq * 16 + col;
        bI[cq] = ball[c]; bF[cq] = ball[64 + c]; bT[cq] = ball[128 + c]; bO[cq] = ball[192 + c];
    }
#pragma unroll
    for (int r = 0; r < 4; r++) {
        int node = m0 + quad * 4 + r;
        if (node >= N_NODES) continue;
#pragma unroll
        for (int cq = 0; cq < 4; cq++) {
            int c = cq * 16 + col;
            float ig = fsig(acc[0 + cq][r]  + bI[cq]);
            float fg = fsig(acc[4 + cq][r]  + bF[cq]);
            float tg = ftanh(acc[8 + cq][r] + bT[cq]);
            float og = fsig(acc[12 + cq][r] + bO[cq]);
            float cv = fmaf(fg, C[(size_t)node * 64 + c], ig * tg);
            out[(size_t)node * 64 + c] = og * ftanh(cv);
            out[(size_t)N_NODES * 64 + (size_t)node * 64 + c] = cv;
        }
    }
}

// ---------------------------------------------------------------- launch

extern "C" void kernel_launch(void* const* d_in, const int* in_sizes, int n_in,
                              void* d_out, int out_size, void* d_ws, size_t ws_size,
                              hipStream_t stream) {
    const float* X   = (const float*)d_in[0];
    const void*  ei  = d_in[1];
    const float* w   = (const float*)d_in[2];
    const float* H   = (const float*)d_in[3];
    const float* C   = (const float*)d_in[4];
    const float* Wxi = (const float*)d_in[5];  const float* bxi = (const float*)d_in[6];
    const float* Whi = (const float*)d_in[7];  const float* bhi = (const float*)d_in[8];
    const float* Wxf = (const float*)d_in[9];  const float* bxf = (const float*)d_in[10];
    const float* Whf = (const float*)d_in[11]; const float* bhf = (const float*)d_in[12];
    const float* Wxc = (const float*)d_in[13]; const float* bxc = (const float*)d_in[14];
    const float* Whc = (const float*)d_in[15]; const float* bhc = (const float*)d_in[16];
    const float* Wxo = (const float*)d_in[17]; const float* bxo = (const float*)d_in[18];
    const float* Who = (const float*)d_in[19]; const float* bho = (const float*)d_in[20];
    const float* bgi = (const float*)d_in[21]; const float* bgf = (const float*)d_in[22];
    const float* bgc = (const float*)d_in[23]; const float* bgo = (const float*)d_in[24];
    float* out = (float*)d_out;

    char* ws = (char*)d_ws;
    size_t off = 0;
    auto alloc = [&](size_t bytes) -> char* {
        char* p = ws + off;
        off = (off + bytes + 255) & ~(size_t)255;
        return p;
    };
    unsigned* hist  = (unsigned*)alloc((size_t)NBKT * NBE4 * 4);
    unsigned* btot  = (unsigned*)alloc((NBKT + 1) * 4);
    unsigned* bbase = (unsigned*)alloc((NBKT + 1) * 4);
    unsigned long long* ebuf = (unsigned long long*)alloc((size_t)N_EDGES * 8);
    int*   rp   = (int*)alloc((N_NODES + 1) * 4);
    float* dinv = (float*)alloc(N_NODES * 4);
    int*   colp = (int*)alloc((size_t)(N_EDGES + 8) * 4);
    float* wraw = (float*)alloc((size_t)(N_EDGES + 8) * 4);
    float* nwp  = (float*)alloc((size_t)(N_EDGES + 8) * 4);
    unsigned short* XH = (unsigned short*)alloc((size_t)N_PAD * 128 * 2);
    unsigned short* U1 = (unsigned short*)alloc((size_t)N_PAD * 128 * 2);
    unsigned short* U2 = (unsigned short*)alloc((size_t)N_PAD * 128 * 2);
    unsigned short* Wf = (unsigned short*)alloc((size_t)12 * 16 * 64 * 8 * 2);
    float* ball = (float*)alloc(256 * 4);
    (void)ws_size; (void)in_sizes; (void)n_in; (void)out_size;

    k_prep<<<NBE4 + NB_IL2 + 49, 256, 0, stream>>>(ei, hist, X, H, XH,
                                                   Wxi, Whi, Wxf, Whf, Wxc, Whc, Wxo, Who,
                                                   bxi, bhi, bxf, bhf, bxc, bhc, bxo, bho,
                                                   bgi, bgf, bgc, bgo, Wf, ball);
    k_bscan<<<NBKT, 256, 0, stream>>>(hist, btot);
    k_btot<<<1, 256, 0, stream>>>(btot, bbase, rp);
    k_scat<<<NBE4, 256, 0, stream>>>(ei, w, hist, bbase, ebuf);
    k_build<<<NBKT, 1024, 0, stream>>>(ebuf, bbase, rp, dinv, colp, wraw);
    k_nw<<<(N_EDGES + 255) / 256, 256, 0, stream>>>(colp, wraw, dinv, nwp);
    k_spmv_bf<<<(N_NODES + 3) / 4, 256, 0, stream>>>(XH, U1, rp, colp, nwp);
    k_spmv_bf<<<(N_NODES + 3) / 4, 256, 0, stream>>>(U1, U2, rp, colp, nwp);
    k_gemm_mfma<<<(N_NODES + 63) / 64, 256, 0, stream>>>(XH, U1, U2, Wf, ball, C, out);
}